// Round 2
// baseline (18343.788 us; speedup 1.0000x reference)
//
#include <hip/hip_runtime.h>

// HMM forward: alpha_t = (alpha_{t-1} @ A) * B[:, obs_t], out = sum(alpha_{T-1})
// S=2048, V=32768, T=4096. Persistent cooperative kernel, latency-optimized.
//
// R1 changes vs R0:
//  - A fragment PINNED in VGPRs via asm barrier (R0 had VGPR_Count=56 -> the
//    compiler was re-loading A from L2 every step, ~128KB/block/step).
//  - Wave-owns-2-columns: each wave computes, reduces (shfl_xor x5) and
//    publishes its own columns. Removes barrier #2 + LDS partial round trip +
//    serial wave-0 epilogue from the per-step critical path.

#define S 2048
#define V 32768
#define T 4096
#define G 128          // blocks, cooperative => co-resident
#define BT 512         // 8 waves
#define COLS 16        // columns of A per block
#define RPT 64         // rows of A per thread
#define RING 16        // b-value ring slots
#define DIST 8         // b prefetch distance (steps)

__global__ __launch_bounds__(BT, 2) void hmm_fwd(
    const int* __restrict__ obs,
    const float* __restrict__ A,
    const float* __restrict__ B,
    const float* __restrict__ pi,
    float* __restrict__ out,
    unsigned long long* __restrict__ buf)   // 2 * S pairs of {tag32, f32}
{
    const int g    = blockIdx.x;
    const int tid  = threadIdx.x;
    const int lane = tid & 63;
    const int wave = tid >> 6;
    const int q    = lane & 31;          // 32-row-group within column
    const int half = lane >> 5;          // which of the wave's 2 columns
    const int c    = 2 * wave + half;    // column-within-block 0..15
    const int j    = g * COLS + c;       // global column index

    // alpha as float4; float4 #p stored at index p + (p>>4) (conflict-benign)
    __shared__ float4 lds_alpha[544];
    __shared__ float  bring[RING * 16];  // prefetched B[j, obs_t]
    __shared__ float  partial[8];        // final-reduce scratch (block 0)

    // ---- load A fragment: rows [q*64, q*64+64) of column j, then PIN in VGPRs
    float a[RPT];
    {
        const float* Ap = A + (q * RPT) * S + j;
#pragma unroll
        for (int k = 0; k < RPT; ++k) a[k] = Ap[k * S];
#pragma unroll
        for (int k = 0; k < RPT; ++k) asm volatile("" : "+v"(a[k]));
    }

    // ---- publishers (q==0; 2 per wave, cover all 16 columns):
    //      init b-ring for t=1..DIST and publish alpha_0 (tag 1)
    if (q == 0) {
        for (int u = 1; u <= DIST; ++u) {
            int o = obs[u];
            bring[(u & (RING - 1)) * 16 + c] = B[j * V + o];
        }
        int o0 = obs[0];
        float v = pi[j] * B[j * V + o0];
        unsigned long long p = (1ull << 32) | (unsigned long long)__float_as_uint(v);
        __hip_atomic_store(&buf[j], p, __ATOMIC_RELAXED, __HIP_MEMORY_SCOPE_AGENT);
    }

    for (int t = 1; t < T; ++t) {
        // ---- poll + stage alpha_{t-1} (tag == t); each thread owns 4 entries
        unsigned long long want = (unsigned long long)t;
        unsigned long long* src = buf + (((t - 1) & 1) * S) + 4 * tid;
        unsigned long long v0, v1, v2, v3;
        for (;;) {
            v0 = __hip_atomic_load(&src[0], __ATOMIC_RELAXED, __HIP_MEMORY_SCOPE_AGENT);
            v1 = __hip_atomic_load(&src[1], __ATOMIC_RELAXED, __HIP_MEMORY_SCOPE_AGENT);
            v2 = __hip_atomic_load(&src[2], __ATOMIC_RELAXED, __HIP_MEMORY_SCOPE_AGENT);
            v3 = __hip_atomic_load(&src[3], __ATOMIC_RELAXED, __HIP_MEMORY_SCOPE_AGENT);
            if ((v0 >> 32) == want && (v1 >> 32) == want &&
                (v2 >> 32) == want && (v3 >> 32) == want) break;
            __builtin_amdgcn_s_sleep(1);
        }
        float4 f;
        f.x = __uint_as_float((unsigned)v0);
        f.y = __uint_as_float((unsigned)v1);
        f.z = __uint_as_float((unsigned)v2);
        f.w = __uint_as_float((unsigned)v3);
        lds_alpha[tid + (tid >> 4)] = f;
        __syncthreads();   // the ONLY per-step barrier: alpha staged

        // ---- prefetch b_{t+DIST} for this wave's columns (overlaps FMA)
        if (q == 0) {
            int tp = t + DIST;
            if (tp < T) {
                int o = obs[tp];
                bring[(tp & (RING - 1)) * 16 + c] = B[j * V + o];
            }
        }

        // ---- dot: 64 rows of column j against staged alpha
        float acc = 0.f;
#pragma unroll
        for (int k = 0; k < 16; ++k) {
            float4 al = lds_alpha[17 * q + k];
            acc = fmaf(al.x, a[4 * k + 0], acc);
            acc = fmaf(al.y, a[4 * k + 1], acc);
            acc = fmaf(al.z, a[4 * k + 2], acc);
            acc = fmaf(al.w, a[4 * k + 3], acc);
        }
        // reduce over the 32 lanes of this column-half
        acc += __shfl_xor(acc, 16, 64);
        acc += __shfl_xor(acc, 8, 64);
        acc += __shfl_xor(acc, 4, 64);
        acc += __shfl_xor(acc, 2, 64);
        acc += __shfl_xor(acc, 1, 64);

        // ---- publish: apply b_t, store {tag=t+1, value}
        if (q == 0) {
            float val = acc * bring[(t & (RING - 1)) * 16 + c];
            unsigned long long p = (((unsigned long long)(t + 1)) << 32) |
                                   (unsigned long long)__float_as_uint(val);
            __hip_atomic_store(&buf[(t & 1) * S + j], p,
                               __ATOMIC_RELAXED, __HIP_MEMORY_SCOPE_AGENT);
        }
    }

    // ---- final: block 0 sums alpha_{T-1} (tag == T) into out[0]
    if (g == 0) {
        unsigned long long want = (unsigned long long)T;
        unsigned long long* src = buf + (((T - 1) & 1) * S) + 4 * tid;
        unsigned long long v0, v1, v2, v3;
        for (;;) {
            v0 = __hip_atomic_load(&src[0], __ATOMIC_RELAXED, __HIP_MEMORY_SCOPE_AGENT);
            v1 = __hip_atomic_load(&src[1], __ATOMIC_RELAXED, __HIP_MEMORY_SCOPE_AGENT);
            v2 = __hip_atomic_load(&src[2], __ATOMIC_RELAXED, __HIP_MEMORY_SCOPE_AGENT);
            v3 = __hip_atomic_load(&src[3], __ATOMIC_RELAXED, __HIP_MEMORY_SCOPE_AGENT);
            if ((v0 >> 32) == want && (v1 >> 32) == want &&
                (v2 >> 32) == want && (v3 >> 32) == want) break;
            __builtin_amdgcn_s_sleep(1);
        }
        float sm = __uint_as_float((unsigned)v0) + __uint_as_float((unsigned)v1) +
                   __uint_as_float((unsigned)v2) + __uint_as_float((unsigned)v3);
        sm += __shfl_down(sm, 32, 64);
        sm += __shfl_down(sm, 16, 64);
        sm += __shfl_down(sm, 8, 64);
        sm += __shfl_down(sm, 4, 64);
        sm += __shfl_down(sm, 2, 64);
        sm += __shfl_down(sm, 1, 64);
        if (lane == 0) partial[wave] = sm;
        __syncthreads();
        if (tid == 0) {
            float tot = 0.f;
            for (int w = 0; w < 8; ++w) tot += partial[w];
            out[0] = tot;
        }
    }
}

extern "C" void kernel_launch(void* const* d_in, const int* in_sizes, int n_in,
                              void* d_out, int out_size, void* d_ws, size_t ws_size,
                              hipStream_t stream) {
    const int*   obs = (const int*)d_in[0];
    const float* A   = (const float*)d_in[1];
    const float* B   = (const float*)d_in[2];
    const float* pi  = (const float*)d_in[3];
    float* out = (float*)d_out;
    unsigned long long* buf = (unsigned long long*)d_ws;  // 2*S*8 = 32 KB

    // No memset needed: 0xAA poison tag 0xAAAAAAAA never matches tags [1,4096].

    void* args[] = { (void*)&obs, (void*)&A, (void*)&B, (void*)&pi,
                     (void*)&out, (void*)&buf };
    hipLaunchCooperativeKernel((void*)hmm_fwd, dim3(G), dim3(BT), args, 0, stream);
}